// Round 3
// baseline (1489.680 us; speedup 1.0000x reference)
//
#include <hip/hip_runtime.h>
#include <stdint.h>

// Problem constants (GatedGraphConv_26585847562966)
#define NN  100000   // nodes
#define DD  128      // feature dim
#define TT  3        // timesteps
#define ETT 4        // edge types
#define EE  250000   // edges per type
#define NCH 49       // scan chunks per edge type (2048 elems each)

typedef float  f32x4  __attribute__((ext_vector_type(4)));
typedef __bf16 bf16x8 __attribute__((ext_vector_type(8)));

__device__ __forceinline__ float bf2f(uint32_t u){ u <<= 16; return __builtin_bit_cast(float, u); }
__device__ __forceinline__ uint32_t f2bf(float f){
  uint32_t u = __builtin_bit_cast(uint32_t, f);
  return (u + 0x7FFFu + ((u >> 16) & 1u)) >> 16;   // RNE, low 16 bits valid
}
__device__ __forceinline__ f32x4 mfma16(bf16x8 a, bf16x8 b, f32x4 c){
  return __builtin_amdgcn_mfma_f32_16x16x32_bf16(a, b, c, 0, 0, 0);
}

// ---------------------------------------------------------------- CSR build
__global__ void k_count(const int* __restrict__ erow, const float* __restrict__ eval,
                        int* __restrict__ counts, float* __restrict__ degval){
  int idx = blockIdx.x * 256 + threadIdx.x;
  if (idx >= ETT * EE) return;
  int e = idx / EE;
  int row = erow[idx];
  atomicAdd(&counts[e * NN + row], 1);
  atomicAdd(&degval[e * NN + row], eval[idx]);
}

// per-chunk sums (grid = ETT*NCH blocks x 256)
__global__ void k_blksum(const int* __restrict__ counts, int* __restrict__ bsum){
  const int b = blockIdx.x, e = b / NCH, c = b % NCH;
  const int* p = counts + e * NN + c * 2048;
  int lim = NN - c * 2048; if (lim > 2048) lim = 2048;
  const int t = threadIdx.x;
  int s = 0;
  #pragma unroll
  for (int i = 0; i < 8; ++i){
    int idx = i * 256 + t;
    if (idx < lim) s += p[idx];
  }
  #pragma unroll
  for (int d = 32; d; d >>= 1) s += __shfl_down(s, d);
  __shared__ int wsum[4];
  if ((t & 63) == 0) wsum[t >> 6] = s;
  __syncthreads();
  if (t == 0) bsum[b] = wsum[0] + wsum[1] + wsum[2] + wsum[3];
}

// scan the 49 chunk-sums per edge type (1 block, wave per etype)
__global__ void k_scanp(const int* __restrict__ bsum, int* __restrict__ bexc,
                        int* __restrict__ offsets){
  const int t = threadIdx.x, wid = t >> 6, l = t & 63;
  int v = (l < NCH) ? bsum[wid * NCH + l] : 0;
  int x = v;
  #pragma unroll
  for (int d = 1; d < 64; d <<= 1){ int y = __shfl_up(x, d); if (l >= d) x += y; }
  if (l < NCH) bexc[wid * NCH + l] = x - v;
  if (l == NCH - 1) offsets[wid * (NN + 1) + NN] = x;
}

// per-chunk exclusive scan + chunk offset (grid = ETT*NCH x 256)
__global__ void k_apply(const int* __restrict__ counts, const int* __restrict__ bexc,
                        int* __restrict__ offsets){
  const int b = blockIdx.x, e = b / NCH, c = b % NCH;
  const int* p = counts + e * NN + c * 2048;
  int* off = offsets + e * (NN + 1) + c * 2048;
  int lim = NN - c * 2048; if (lim > 2048) lim = 2048;
  const int t = threadIdx.x, l = t & 63, wid = t >> 6;
  __shared__ int wt[4];
  int v[8], s = 0;
  #pragma unroll
  for (int i = 0; i < 8; ++i){
    int idx = t * 8 + i;
    v[i] = (idx < lim) ? p[idx] : 0; s += v[i];
  }
  int x = s;
  #pragma unroll
  for (int d = 1; d < 64; d <<= 1){ int y = __shfl_up(x, d); if (l >= d) x += y; }
  if (l == 63) wt[wid] = x;
  __syncthreads();
  int wexc = 0;
  #pragma unroll
  for (int k = 0; k < 4; ++k) if (k < wid) wexc += wt[k];
  int te = bexc[b] + wexc + (x - s);
  #pragma unroll
  for (int i = 0; i < 8; ++i){
    int idx = t * 8 + i;
    if (idx < lim) off[idx] = te;
    te += v[i];
  }
}

__global__ void k_fill(const int* __restrict__ erow, const int* __restrict__ ecol,
                       const float* __restrict__ eval, const int* __restrict__ offsets,
                       int* __restrict__ cursor, uint2* __restrict__ sedge){
  int idx = blockIdx.x * 256 + threadIdx.x;
  if (idx >= ETT * EE) return;
  int e = idx / EE;
  int row = erow[idx];
  int pos = atomicAdd(&cursor[e * NN + row], 1);
  int o = offsets[e * (NN + 1) + row] + pos;
  sedge[e * EE + o] = make_uint2((uint32_t)ecol[idx], __builtin_bit_cast(uint32_t, eval[idx]));
}

// ---------------------------------------------------------------- converts
__global__ void k_conv_x(const float* __restrict__ x, uint16_t* __restrict__ hbf){
  int idx = blockIdx.x * 256 + threadIdx.x;       // one uint4 (8 bf16) per thread
  const float4* xp = (const float4*)x;
  float4 a = xp[idx * 2], b = xp[idx * 2 + 1];
  uint32_t p0 = f2bf(a.x) | (f2bf(a.y) << 16);
  uint32_t p1 = f2bf(a.z) | (f2bf(a.w) << 16);
  uint32_t p2 = f2bf(b.x) | (f2bf(b.y) << 16);
  uint32_t p3 = f2bf(b.z) | (f2bf(b.w) << 16);
  ((uint4*)hbf)[idx] = make_uint4(p0, p1, p2, p3);
}

// wcatT[t][f][e*128+d] = weight[t][e][d][f]   (B^T layout: contiguous-k fragments)
__global__ void k_conv_w(const float* __restrict__ weight, const float* __restrict__ wih,
                         const float* __restrict__ whh, const float* __restrict__ bih,
                         const float* __restrict__ bhh, uint16_t* __restrict__ wcatT,
                         uint16_t* __restrict__ wihb, uint16_t* __restrict__ whhb,
                         float* __restrict__ bcomb){
  int idx = blockIdx.x * 256 + threadIdx.x;
  if (idx < TT * 128 * 512){
    int t = idx / 65536; int rem = idx - t * 65536;
    int f = rem >> 9; int u = rem & 511;
    int e = u >> 7; int d = u & 127;
    wcatT[idx] = (uint16_t)f2bf(weight[(((t * 4 + e) * 128 + d) << 7) + f]);
  }
  if (idx < 384 * 128){
    wihb[idx] = (uint16_t)f2bf(wih[idx]);
    whhb[idx] = (uint16_t)f2bf(whh[idx]);
  }
  if (idx < 256) bcomb[idx] = bih[idx] + bhh[idx];
}

// ------------------------------------------------- fused gather + GEMM1
// m_sum[n,f] = sum_{e,d} agg[e,n,d] * W[t,e,d,f] + sum_e deg[e,n]*bias_w[t,e,f]
__global__ __launch_bounds__(256, 4) void k_agg_gemm(
    const uint16_t* __restrict__ hbf, const int* __restrict__ offsets,
    const uint2* __restrict__ sedge, const float* __restrict__ degval,
    const float* __restrict__ bias_w, const uint16_t* __restrict__ wcatT_t,
    int tstep, uint16_t* __restrict__ m_out)
{
  __shared__ uint16_t aggT[32 * 512];             // 32 KiB, 16B-chunk XOR-swizzled
  const int tid = threadIdx.x;
  const int node0 = blockIdx.x * 32;              // 100000/32 = 3125 blocks exact

  { // gather: thread = (node nl of 32, eighth q of 16 dims)
    const int nl = tid >> 3, q = tid & 7;
    const int n = node0 + nl;
    #pragma unroll 1
    for (int e = 0; e < ETT; ++e){
      float acc[16];
      #pragma unroll
      for (int i = 0; i < 16; ++i) acc[i] = 0.f;
      const int s  = offsets[e * (NN + 1) + n];
      const int en = offsets[e * (NN + 1) + n + 1];
      for (int i = s; i < en; ++i){
        const uint2 cv = sedge[e * EE + i];
        const float val = __builtin_bit_cast(float, cv.y);
        const uint4* hp = (const uint4*)(hbf + (size_t)cv.x * DD + q * 16);
        uint4 u0 = hp[0], u1 = hp[1];
        acc[0]  += val * bf2f(u0.x & 0xffffu);  acc[1]  += val * bf2f(u0.x >> 16);
        acc[2]  += val * bf2f(u0.y & 0xffffu);  acc[3]  += val * bf2f(u0.y >> 16);
        acc[4]  += val * bf2f(u0.z & 0xffffu);  acc[5]  += val * bf2f(u0.z >> 16);
        acc[6]  += val * bf2f(u0.w & 0xffffu);  acc[7]  += val * bf2f(u0.w >> 16);
        acc[8]  += val * bf2f(u1.x & 0xffffu);  acc[9]  += val * bf2f(u1.x >> 16);
        acc[10] += val * bf2f(u1.y & 0xffffu);  acc[11] += val * bf2f(u1.y >> 16);
        acc[12] += val * bf2f(u1.z & 0xffffu);  acc[13] += val * bf2f(u1.z >> 16);
        acc[14] += val * bf2f(u1.w & 0xffffu);  acc[15] += val * bf2f(u1.w >> 16);
      }
      #pragma unroll
      for (int c2 = 0; c2 < 2; ++c2){
        const int c  = e * 16 + q * 2 + c2;       // logical 16B chunk (0..63)
        const int cs = c ^ (nl & 7);
        uint32_t p0 = f2bf(acc[c2*8+0]) | (f2bf(acc[c2*8+1]) << 16);
        uint32_t p1 = f2bf(acc[c2*8+2]) | (f2bf(acc[c2*8+3]) << 16);
        uint32_t p2 = f2bf(acc[c2*8+4]) | (f2bf(acc[c2*8+5]) << 16);
        uint32_t p3 = f2bf(acc[c2*8+6]) | (f2bf(acc[c2*8+7]) << 16);
        *(uint4*)&aggT[nl * 512 + cs * 8] = make_uint4(p0, p1, p2, p3);
      }
    }
  }
  __syncthreads();

  // GEMM: C[32x128] = aggT[32x512] * Wcat[512x128]
  // wave w: row-tile rt = w&1 (16 rows), f-half fh = w>>1 (64 cols = 4 f-tiles)
  const int lane = tid & 63, w = tid >> 6;
  const int rlo = lane & 15, kg = lane >> 4;
  const int rt = w & 1, fh = w >> 1;
  const int rowA = rt * 16 + rlo;
  f32x4 C[4];
  #pragma unroll
  for (int i = 0; i < 4; ++i) C[i] = f32x4{0.f, 0.f, 0.f, 0.f};

  #pragma unroll
  for (int ks = 0; ks < 16; ++ks){
    const int cs = (ks * 4 + kg) ^ (rowA & 7);
    bf16x8 a = __builtin_bit_cast(bf16x8, *(const uint4*)&aggT[rowA * 512 + cs * 8]);
    #pragma unroll
    for (int ft = 0; ft < 4; ++ft){
      const int f = fh * 64 + ft * 16 + rlo;
      bf16x8 b = __builtin_bit_cast(bf16x8, *(const uint4*)(wcatT_t + (size_t)f * 512 + ks * 32 + kg * 8));
      C[ft] = mfma16(a, b, C[ft]);
    }
  }

  const float* bwt = bias_w + tstep * (ETT * DD);
  float dv[4][4];
  #pragma unroll
  for (int r = 0; r < 4; ++r){
    const int n2 = node0 + rt * 16 + kg * 4 + r;
    #pragma unroll
    for (int e = 0; e < 4; ++e) dv[e][r] = degval[e * NN + n2];
  }
  #pragma unroll
  for (int ft = 0; ft < 4; ++ft){
    const int f = fh * 64 + ft * 16 + rlo;
    const float b0 = bwt[f], b1 = bwt[128 + f], b2 = bwt[256 + f], b3 = bwt[384 + f];
    #pragma unroll
    for (int r = 0; r < 4; ++r){
      const int n2 = node0 + rt * 16 + kg * 4 + r;
      const float bias = dv[0][r]*b0 + dv[1][r]*b1 + dv[2][r]*b2 + dv[3][r]*b3;
      m_out[(size_t)n2 * DD + f] = (uint16_t)f2bf(C[ft][r] + bias);
    }
  }
}

// ------------------------------------------------- weight-stationary GRU
// Block = 512 thr (8 waves), owns dim-half dh (64 dims) of all 3 gates for BOTH
// matrices: 384 rows x 128 k = 96 KiB LDS, staged once, XOR-swizzled.
// Each wave grid-strides over 16-node tiles; lane (rlo,kg) ends up holding
// ir/iz/in/hr/hz/hn for node (tile*16+rlo), d = dh*64 + dblk*16 + kg*4 + r.
// hbf is ping-ponged across dispatches (hsrc read-only, hdst write-only).
__global__ __launch_bounds__(512, 2) void k_gru(
    const uint16_t* __restrict__ m_sum, const uint16_t* __restrict__ hsrc,
    uint16_t* __restrict__ hdst, const float* __restrict__ h_old,
    float* __restrict__ h_new, const uint16_t* __restrict__ wihb,
    const uint16_t* __restrict__ whhb, const float* __restrict__ bcomb,
    const float* __restrict__ b_ih, const float* __restrict__ b_hh)
{
  __shared__ uint16_t wlds[384 * 128];            // 96 KiB
  const int tid = threadIdx.x;
  const int dh  = blockIdx.x & 1;                 // dim-half
  const int blk = blockIdx.x >> 1;                // 0..127

  // stage weights: slice row s = mat*192 + g*64 + dd  (dd in [0,64))
  #pragma unroll
  for (int i = 0; i < 12; ++i){
    const int ci = i * 512 + tid;                 // 6144 16B-chunks total
    const int s = ci >> 4, c = ci & 15;
    const int m = (s >= 192) ? 1 : 0;
    const int r = s - m * 192;
    const int jglob = (r >> 6) * 128 + dh * 64 + (r & 63);
    const uint16_t* src = (m ? whhb : wihb) + jglob * 128 + c * 8;
    *(uint4*)&wlds[s * 128 + ((c ^ (s & 7)) << 3)] = *(const uint4*)src;
  }
  __syncthreads();

  const int lane = tid & 63, w = tid >> 6;
  const int rlo = lane & 15, kg = lane >> 4;
  const int wv = blk * 8 + w;                     // 0..1023 (per dim-half)

  #pragma unroll 1
  for (int tile = wv; tile < NN / 16; tile += 1024){
    const int row = tile * 16 + rlo;
    const uint16_t* mrow = m_sum + (size_t)row * DD;
    const uint16_t* hrow = hsrc  + (size_t)row * DD;

    uint4 bmv[4], bhv[4];
    #pragma unroll
    for (int ks = 0; ks < 4; ++ks){
      bmv[ks] = *(const uint4*)(mrow + ks * 32 + kg * 8);
      bhv[ks] = *(const uint4*)(hrow + ks * 32 + kg * 8);
    }

    f32x4 acc[4][6];                              // [dblk][g*2+mat]
    #pragma unroll
    for (int a = 0; a < 4; ++a)
      #pragma unroll
      for (int b = 0; b < 6; ++b) acc[a][b] = f32x4{0.f,0.f,0.f,0.f};

    #pragma unroll
    for (int ks = 0; ks < 4; ++ks){
      const bf16x8 bm = __builtin_bit_cast(bf16x8, bmv[ks]);
      const bf16x8 bh = __builtin_bit_cast(bf16x8, bhv[ks]);
      #pragma unroll
      for (int dblk = 0; dblk < 4; ++dblk){
        #pragma unroll
        for (int g = 0; g < 3; ++g){
          const int s0 = g * 64 + dblk * 16 + rlo;          // wih row; whh = +192
          const int cc = ((ks * 4 + kg) ^ (s0 & 7)) << 3;
          bf16x8 fa = __builtin_bit_cast(bf16x8, *(const uint4*)&wlds[s0 * 128 + cc]);
          acc[dblk][g*2]   = mfma16(fa, bm, acc[dblk][g*2]);
          bf16x8 fb = __builtin_bit_cast(bf16x8, *(const uint4*)&wlds[(192 + s0) * 128 + cc]);
          acc[dblk][g*2+1] = mfma16(fb, bh, acc[dblk][g*2+1]);
        }
      }
    }

    #pragma unroll
    for (int dblk = 0; dblk < 4; ++dblk){
      const int d0 = dh * 64 + dblk * 16 + kg * 4;
      const f32x4 brz = *(const f32x4*)(bcomb + d0);
      const f32x4 bzz = *(const f32x4*)(bcomb + 128 + d0);
      const f32x4 bin = *(const f32x4*)(b_ih + 256 + d0);
      const f32x4 bhn = *(const f32x4*)(b_hh + 256 + d0);
      const f32x4 ho  = *(const f32x4*)(h_old + (size_t)row * DD + d0);
      float hv[4];
      #pragma unroll
      for (int r = 0; r < 4; ++r){
        const float rg = 1.f / (1.f + __expf(-(acc[dblk][0][r] + acc[dblk][1][r] + brz[r])));
        const float zg = 1.f / (1.f + __expf(-(acc[dblk][2][r] + acc[dblk][3][r] + bzz[r])));
        const float xa = (acc[dblk][4][r] + bin[r]) + rg * (acc[dblk][5][r] + bhn[r]);
        const float ng = 1.f - 2.f / (__expf(2.f * xa) + 1.f);   // tanh
        hv[r] = (1.f - zg) * ng + zg * ho[r];
      }
      *(f32x4*)(h_new + (size_t)row * DD + d0) = f32x4{hv[0], hv[1], hv[2], hv[3]};
      uint32_t p0 = f2bf(hv[0]) | (f2bf(hv[1]) << 16);
      uint32_t p1 = f2bf(hv[2]) | (f2bf(hv[3]) << 16);
      *(uint2*)(hdst + (size_t)row * DD + d0) = make_uint2(p0, p1);
    }
  }
}

// ---------------------------------------------------------------- launch
extern "C" void kernel_launch(void* const* d_in, const int* in_sizes, int n_in,
                              void* d_out, int out_size, void* d_ws, size_t ws_size,
                              hipStream_t stream) {
  const float* x      = (const float*)d_in[0];
  const int*   erow   = (const int*)d_in[1];
  const int*   ecol   = (const int*)d_in[2];
  const float* eval   = (const float*)d_in[3];
  const float* weight = (const float*)d_in[4];
  const float* bias_w = (const float*)d_in[5];
  const float* wih    = (const float*)d_in[6];
  const float* whh    = (const float*)d_in[7];
  const float* bih    = (const float*)d_in[8];
  const float* bhh    = (const float*)d_in[9];
  float* out = (float*)d_out;
  char* ws = (char*)d_ws;

  size_t o = 0;
  auto alloc = [&](size_t bytes)->char*{ char* p = ws + o; o += (bytes + 255) & ~(size_t)255; return p; };
  int*      counts  = (int*)     alloc((size_t)ETT * NN * 4);        // zeroed
  int*      cursor  = (int*)     alloc((size_t)ETT * NN * 4);        // zeroed
  float*    degval  = (float*)   alloc((size_t)ETT * NN * 4);        // zeroed
  int*      offsets = (int*)     alloc((size_t)ETT * (NN + 1) * 4);
  int*      bsum    = (int*)     alloc((size_t)ETT * NCH * 4);
  int*      bexc    = (int*)     alloc((size_t)ETT * NCH * 4);
  uint2*    sedge   = (uint2*)   alloc((size_t)ETT * EE * 8);
  float*    hf      = (float*)   alloc((size_t)NN * DD * 4);
  uint16_t* hbf0    = (uint16_t*)alloc((size_t)NN * DD * 2);
  uint16_t* hbf1    = (uint16_t*)alloc((size_t)NN * DD * 2);
  uint16_t* msum    = (uint16_t*)alloc((size_t)NN * DD * 2);
  uint16_t* wcatT   = (uint16_t*)alloc((size_t)TT * 128 * 512 * 2);
  uint16_t* wihb    = (uint16_t*)alloc((size_t)384 * 128 * 2);
  uint16_t* whhb    = (uint16_t*)alloc((size_t)384 * 128 * 2);
  float*    bcomb   = (float*)   alloc((size_t)256 * 4);
  (void)ws_size; (void)in_sizes; (void)n_in; (void)out_size;

  // counts/cursor/degval contiguous (each 1.6MB, 256-aligned exactly)
  hipMemsetAsync(counts, 0, (size_t)3 * ETT * NN * 4, stream);

  k_count<<<(ETT * EE + 255) / 256, 256, 0, stream>>>(erow, eval, counts, degval);
  k_blksum<<<ETT * NCH, 256, 0, stream>>>(counts, bsum);
  k_scanp<<<1, 256, 0, stream>>>(bsum, bexc, offsets);
  k_apply<<<ETT * NCH, 256, 0, stream>>>(counts, bexc, offsets);
  k_fill<<<(ETT * EE + 255) / 256, 256, 0, stream>>>(erow, ecol, eval, offsets, cursor, sedge);
  k_conv_x<<<(NN * DD / 8) / 256, 256, 0, stream>>>(x, hbf0);
  k_conv_w<<<(TT * 128 * 512 + 255) / 256, 256, 0, stream>>>(weight, wih, whh, bih, bhh,
                                                             wcatT, wihb, whhb, bcomb);

  uint16_t* hsrc = hbf0;
  uint16_t* hdst = hbf1;
  for (int t = 0; t < TT; ++t){
    k_agg_gemm<<<NN / 32, 256, 0, stream>>>(hsrc, offsets, sedge, degval,
                                            bias_w, wcatT + (size_t)t * 65536, t, msum);
    const float* hold = (t == 0) ? x : hf;
    float* hnew = (t == TT - 1) ? out : hf;
    k_gru<<<256, 512, 0, stream>>>(msum, hsrc, hdst, hold, hnew,
                                   wihb, whhb, bcomb, bih, bhh);
    uint16_t* tmp = hsrc; hsrc = hdst; hdst = tmp;
  }
}

// Round 4
// 773.638 us; speedup vs baseline: 1.9256x; 1.9256x over previous
//
#include <hip/hip_runtime.h>
#include <stdint.h>

// Problem constants (GatedGraphConv_26585847562966)
#define NN  100000   // nodes
#define DD  128      // feature dim
#define TT  3        // timesteps
#define ETT 4        // edge types
#define EE  250000   // edges per type
#define NCH 49       // scan chunks per edge type (2048 elems each)

typedef float  f32x4  __attribute__((ext_vector_type(4)));
typedef __bf16 bf16x8 __attribute__((ext_vector_type(8)));

__device__ __forceinline__ float bf2f(uint32_t u){ u <<= 16; return __builtin_bit_cast(float, u); }
__device__ __forceinline__ uint32_t f2bf(float f){
  uint32_t u = __builtin_bit_cast(uint32_t, f);
  return (u + 0x7FFFu + ((u >> 16) & 1u)) >> 16;   // RNE, low 16 bits valid
}
__device__ __forceinline__ f32x4 mfma16(bf16x8 a, bf16x8 b, f32x4 c){
  return __builtin_amdgcn_mfma_f32_16x16x32_bf16(a, b, c, 0, 0, 0);
}

// ---------------------------------------------------------------- CSR build
__global__ void k_count(const int* __restrict__ erow, const float* __restrict__ eval,
                        int* __restrict__ counts, float* __restrict__ degval){
  int idx = blockIdx.x * 256 + threadIdx.x;
  if (idx >= ETT * EE) return;
  int e = idx / EE;
  int row = erow[idx];
  atomicAdd(&counts[e * NN + row], 1);
  atomicAdd(&degval[e * NN + row], eval[idx]);
}

// per-chunk sums (grid = ETT*NCH blocks x 256)
__global__ void k_blksum(const int* __restrict__ counts, int* __restrict__ bsum){
  const int b = blockIdx.x, e = b / NCH, c = b % NCH;
  const int* p = counts + e * NN + c * 2048;
  int lim = NN - c * 2048; if (lim > 2048) lim = 2048;
  const int t = threadIdx.x;
  int s = 0;
  #pragma unroll
  for (int i = 0; i < 8; ++i){
    int idx = i * 256 + t;
    if (idx < lim) s += p[idx];
  }
  #pragma unroll
  for (int d = 32; d; d >>= 1) s += __shfl_down(s, d);
  __shared__ int wsum[4];
  if ((t & 63) == 0) wsum[t >> 6] = s;
  __syncthreads();
  if (t == 0) bsum[b] = wsum[0] + wsum[1] + wsum[2] + wsum[3];
}

// scan the 49 chunk-sums per edge type (1 block, wave per etype)
__global__ void k_scanp(const int* __restrict__ bsum, int* __restrict__ bexc,
                        int* __restrict__ offsets){
  const int t = threadIdx.x, wid = t >> 6, l = t & 63;
  int v = (l < NCH) ? bsum[wid * NCH + l] : 0;
  int x = v;
  #pragma unroll
  for (int d = 1; d < 64; d <<= 1){ int y = __shfl_up(x, d); if (l >= d) x += y; }
  if (l < NCH) bexc[wid * NCH + l] = x - v;
  if (l == NCH - 1) offsets[wid * (NN + 1) + NN] = x;
}

// per-chunk exclusive scan + chunk offset (grid = ETT*NCH x 256)
__global__ void k_apply(const int* __restrict__ counts, const int* __restrict__ bexc,
                        int* __restrict__ offsets){
  const int b = blockIdx.x, e = b / NCH, c = b % NCH;
  const int* p = counts + e * NN + c * 2048;
  int* off = offsets + e * (NN + 1) + c * 2048;
  int lim = NN - c * 2048; if (lim > 2048) lim = 2048;
  const int t = threadIdx.x, l = t & 63, wid = t >> 6;
  __shared__ int wt[4];
  int v[8], s = 0;
  #pragma unroll
  for (int i = 0; i < 8; ++i){
    int idx = t * 8 + i;
    v[i] = (idx < lim) ? p[idx] : 0; s += v[i];
  }
  int x = s;
  #pragma unroll
  for (int d = 1; d < 64; d <<= 1){ int y = __shfl_up(x, d); if (l >= d) x += y; }
  if (l == 63) wt[wid] = x;
  __syncthreads();
  int wexc = 0;
  #pragma unroll
  for (int k = 0; k < 4; ++k) if (k < wid) wexc += wt[k];
  int te = bexc[b] + wexc + (x - s);
  #pragma unroll
  for (int i = 0; i < 8; ++i){
    int idx = t * 8 + i;
    if (idx < lim) off[idx] = te;
    te += v[i];
  }
}

__global__ void k_fill(const int* __restrict__ erow, const int* __restrict__ ecol,
                       const float* __restrict__ eval, const int* __restrict__ offsets,
                       int* __restrict__ cursor, uint2* __restrict__ sedge){
  int idx = blockIdx.x * 256 + threadIdx.x;
  if (idx >= ETT * EE) return;
  int e = idx / EE;
  int row = erow[idx];
  int pos = atomicAdd(&cursor[e * NN + row], 1);
  int o = offsets[e * (NN + 1) + row] + pos;
  sedge[e * EE + o] = make_uint2((uint32_t)ecol[idx], __builtin_bit_cast(uint32_t, eval[idx]));
}

// ---------------------------------------------------------------- converts
__global__ void k_conv_x(const float* __restrict__ x, uint16_t* __restrict__ hbf){
  int idx = blockIdx.x * 256 + threadIdx.x;       // one uint4 (8 bf16) per thread
  const float4* xp = (const float4*)x;
  float4 a = xp[idx * 2], b = xp[idx * 2 + 1];
  uint32_t p0 = f2bf(a.x) | (f2bf(a.y) << 16);
  uint32_t p1 = f2bf(a.z) | (f2bf(a.w) << 16);
  uint32_t p2 = f2bf(b.x) | (f2bf(b.y) << 16);
  uint32_t p3 = f2bf(b.z) | (f2bf(b.w) << 16);
  ((uint4*)hbf)[idx] = make_uint4(p0, p1, p2, p3);
}

// wcatT[t][f][e*128+d] = weight[t][e][d][f]   (B^T layout: contiguous-k fragments)
__global__ void k_conv_w(const float* __restrict__ weight, const float* __restrict__ wih,
                         const float* __restrict__ whh, const float* __restrict__ bih,
                         const float* __restrict__ bhh, uint16_t* __restrict__ wcatT,
                         uint16_t* __restrict__ wihb, uint16_t* __restrict__ whhb,
                         float* __restrict__ bcomb){
  int idx = blockIdx.x * 256 + threadIdx.x;
  if (idx < TT * 128 * 512){
    int t = idx / 65536; int rem = idx - t * 65536;
    int f = rem >> 9; int u = rem & 511;
    int e = u >> 7; int d = u & 127;
    wcatT[idx] = (uint16_t)f2bf(weight[(((t * 4 + e) * 128 + d) << 7) + f]);
  }
  if (idx < 384 * 128){
    wihb[idx] = (uint16_t)f2bf(wih[idx]);
    whhb[idx] = (uint16_t)f2bf(whh[idx]);
  }
  if (idx < 256) bcomb[idx] = bih[idx] + bhh[idx];
}

// ------------------------------------------------- fused gather + GEMM1
// m_sum[n,f] = sum_{e,d} agg[e,n,d] * W[t,e,d,f] + sum_e deg[e,n]*bias_w[t,e,f]
__global__ __launch_bounds__(256, 4) void k_agg_gemm(
    const uint16_t* __restrict__ hbf, const int* __restrict__ offsets,
    const uint2* __restrict__ sedge, const float* __restrict__ degval,
    const float* __restrict__ bias_w, const uint16_t* __restrict__ wcatT_t,
    int tstep, uint16_t* __restrict__ m_out)
{
  __shared__ uint16_t aggT[32 * 512];             // 32 KiB, 16B-chunk XOR-swizzled
  const int tid = threadIdx.x;
  const int node0 = blockIdx.x * 32;              // 100000/32 = 3125 blocks exact

  { // gather: thread = (node nl of 32, eighth q of 16 dims)
    const int nl = tid >> 3, q = tid & 7;
    const int n = node0 + nl;
    #pragma unroll 1
    for (int e = 0; e < ETT; ++e){
      float acc[16];
      #pragma unroll
      for (int i = 0; i < 16; ++i) acc[i] = 0.f;
      const int s  = offsets[e * (NN + 1) + n];
      const int en = offsets[e * (NN + 1) + n + 1];
      for (int i = s; i < en; ++i){
        const uint2 cv = sedge[e * EE + i];
        const float val = __builtin_bit_cast(float, cv.y);
        const uint4* hp = (const uint4*)(hbf + (size_t)cv.x * DD + q * 16);
        uint4 u0 = hp[0], u1 = hp[1];
        acc[0]  += val * bf2f(u0.x & 0xffffu);  acc[1]  += val * bf2f(u0.x >> 16);
        acc[2]  += val * bf2f(u0.y & 0xffffu);  acc[3]  += val * bf2f(u0.y >> 16);
        acc[4]  += val * bf2f(u0.z & 0xffffu);  acc[5]  += val * bf2f(u0.z >> 16);
        acc[6]  += val * bf2f(u0.w & 0xffffu);  acc[7]  += val * bf2f(u0.w >> 16);
        acc[8]  += val * bf2f(u1.x & 0xffffu);  acc[9]  += val * bf2f(u1.x >> 16);
        acc[10] += val * bf2f(u1.y & 0xffffu);  acc[11] += val * bf2f(u1.y >> 16);
        acc[12] += val * bf2f(u1.z & 0xffffu);  acc[13] += val * bf2f(u1.z >> 16);
        acc[14] += val * bf2f(u1.w & 0xffffu);  acc[15] += val * bf2f(u1.w >> 16);
      }
      #pragma unroll
      for (int c2 = 0; c2 < 2; ++c2){
        const int c  = e * 16 + q * 2 + c2;       // logical 16B chunk (0..63)
        const int cs = c ^ (nl & 7);
        uint32_t p0 = f2bf(acc[c2*8+0]) | (f2bf(acc[c2*8+1]) << 16);
        uint32_t p1 = f2bf(acc[c2*8+2]) | (f2bf(acc[c2*8+3]) << 16);
        uint32_t p2 = f2bf(acc[c2*8+4]) | (f2bf(acc[c2*8+5]) << 16);
        uint32_t p3 = f2bf(acc[c2*8+6]) | (f2bf(acc[c2*8+7]) << 16);
        *(uint4*)&aggT[nl * 512 + cs * 8] = make_uint4(p0, p1, p2, p3);
      }
    }
  }
  __syncthreads();

  // GEMM: C[32x128] = aggT[32x512] * Wcat[512x128]
  // wave w: row-tile rt = w&1 (16 rows), f-half fh = w>>1 (64 cols = 4 f-tiles)
  const int lane = tid & 63, w = tid >> 6;
  const int rlo = lane & 15, kg = lane >> 4;
  const int rt = w & 1, fh = w >> 1;
  const int rowA = rt * 16 + rlo;
  f32x4 C[4];
  #pragma unroll
  for (int i = 0; i < 4; ++i) C[i] = f32x4{0.f, 0.f, 0.f, 0.f};

  #pragma unroll
  for (int ks = 0; ks < 16; ++ks){
    const int cs = (ks * 4 + kg) ^ (rowA & 7);
    bf16x8 a = __builtin_bit_cast(bf16x8, *(const uint4*)&aggT[rowA * 512 + cs * 8]);
    #pragma unroll
    for (int ft = 0; ft < 4; ++ft){
      const int f = fh * 64 + ft * 16 + rlo;
      bf16x8 b = __builtin_bit_cast(bf16x8, *(const uint4*)(wcatT_t + (size_t)f * 512 + ks * 32 + kg * 8));
      C[ft] = mfma16(a, b, C[ft]);
    }
  }

  const float* bwt = bias_w + tstep * (ETT * DD);
  float dv[4][4];
  #pragma unroll
  for (int r = 0; r < 4; ++r){
    const int n2 = node0 + rt * 16 + kg * 4 + r;
    #pragma unroll
    for (int e = 0; e < 4; ++e) dv[e][r] = degval[e * NN + n2];
  }
  #pragma unroll
  for (int ft = 0; ft < 4; ++ft){
    const int f = fh * 64 + ft * 16 + rlo;
    const float b0 = bwt[f], b1 = bwt[128 + f], b2 = bwt[256 + f], b3 = bwt[384 + f];
    #pragma unroll
    for (int r = 0; r < 4; ++r){
      const int n2 = node0 + rt * 16 + kg * 4 + r;
      const float bias = dv[0][r]*b0 + dv[1][r]*b1 + dv[2][r]*b2 + dv[3][r]*b3;
      m_out[(size_t)n2 * DD + f] = (uint16_t)f2bf(C[ft][r] + bias);
    }
  }
}

// ------------------------------------------------- GRU: weights in VGPRs
// Block = 512 thr (8 waves). Wave w owns dims [w*16, w*16+16) for all 3 gates,
// BOTH matrices: 24 bf16x8 A-fragments = 96 VGPRs, loaded ONCE from global.
// Block grid-strides over 32-node tiles; per tile, m_sum/h rows are staged into
// a double-buffered 2x(8KB+8KB) XOR-swizzled LDS tile (each row read once
// device-wide -> no cross-XCD refetch). Lane (rlo,kg) ends up with all six
// gate pre-activations for node (tile*32+ns*16+rlo), d = w*16+kg*4+r -> full
// GRU epilogue in-lane. hbf ping-pongs across dispatches.
__global__ __launch_bounds__(512, 2) void k_gru(
    const uint16_t* __restrict__ m_sum, const uint16_t* __restrict__ hsrc,
    uint16_t* __restrict__ hdst, const float* __restrict__ h_old,
    float* __restrict__ h_new, const uint16_t* __restrict__ wihb,
    const uint16_t* __restrict__ whhb, const float* __restrict__ bcomb,
    const float* __restrict__ b_ih, const float* __restrict__ b_hh)
{
  __shared__ uint4 mt[2][512];                    // [buf][node*16 + chunk] 8KB each
  __shared__ uint4 ht[2][512];
  const int tid = threadIdx.x;
  const int lane = tid & 63, w = tid >> 6;
  const int rlo = lane & 15, kg = lane >> 4;

  // --- preload weight fragments (persistent in VGPRs) ---
  bf16x8 wa[3][4], wb[3][4];                      // [gate][ks]
  #pragma unroll
  for (int g = 0; g < 3; ++g){
    const int j = g * 128 + w * 16 + rlo;
    #pragma unroll
    for (int ks = 0; ks < 4; ++ks){
      wa[g][ks] = __builtin_bit_cast(bf16x8, *(const uint4*)(wihb + j * 128 + ks * 32 + kg * 8));
      wb[g][ks] = __builtin_bit_cast(bf16x8, *(const uint4*)(whhb + j * 128 + ks * 32 + kg * 8));
    }
  }
  // --- per-lane output dims + biases (constant over tiles) ---
  const int d0 = w * 16 + kg * 4;
  const f32x4 brz = *(const f32x4*)(bcomb + d0);
  const f32x4 bzz = *(const f32x4*)(bcomb + 128 + d0);
  const f32x4 bin = *(const f32x4*)(b_ih + 256 + d0);
  const f32x4 bhn = *(const f32x4*)(b_hh + 256 + d0);

  // --- staging map: thread -> (node sn, LDS slot scs), source chunk sc ---
  const int sn  = tid >> 4;                       // 0..31
  const int scs = tid & 15;                       // swizzled slot
  const int sc  = scs ^ (sn & 7);                 // logical chunk (involution)

  const int NT = NN / 32;                         // 3125
  int tile = blockIdx.x;
  { // prologue: stage tile 0 into buf 0
    const size_t base = ((size_t)(tile * 32 + sn)) * DD + sc * 8;
    mt[0][sn * 16 + scs] = *(const uint4*)(m_sum + base);
    ht[0][sn * 16 + scs] = *(const uint4*)(hsrc + base);
  }
  __syncthreads();

  int buf = 0;
  #pragma unroll 1
  for (; tile < NT; tile += 256){
    // issue next tile's stage loads (consumed after the barrier below)
    const int ntile = tile + 256;
    const bool have = ntile < NT;                 // block-uniform
    uint4 mv, hv;
    if (have){
      const size_t nbase = ((size_t)(ntile * 32 + sn)) * DD + sc * 8;
      mv = *(const uint4*)(m_sum + nbase);
      hv = *(const uint4*)(hsrc + nbase);
    }

    // --- MFMA phase: 48 MFMAs per wave from LDS B-fragments ---
    f32x4 acc[3][2][2];                           // [gate][mat][nsub]
    #pragma unroll
    for (int g = 0; g < 3; ++g)
      #pragma unroll
      for (int m = 0; m < 2; ++m)
        #pragma unroll
        for (int ns = 0; ns < 2; ++ns) acc[g][m][ns] = f32x4{0.f,0.f,0.f,0.f};

    #pragma unroll
    for (int ks = 0; ks < 4; ++ks){
      #pragma unroll
      for (int ns = 0; ns < 2; ++ns){
        const int node = ns * 16 + rlo;
        const int cs = (ks * 4 + kg) ^ (node & 7);
        const bf16x8 bm = __builtin_bit_cast(bf16x8, mt[buf][node * 16 + cs]);
        const bf16x8 bh = __builtin_bit_cast(bf16x8, ht[buf][node * 16 + cs]);
        #pragma unroll
        for (int g = 0; g < 3; ++g){
          acc[g][0][ns] = mfma16(wa[g][ks], bm, acc[g][0][ns]);
          acc[g][1][ns] = mfma16(wb[g][ks], bh, acc[g][1][ns]);
        }
      }
    }

    // --- GRU epilogue, fully in-lane ---
    #pragma unroll
    for (int ns = 0; ns < 2; ++ns){
      const int node = tile * 32 + ns * 16 + rlo;
      const f32x4 ho = *(const f32x4*)(h_old + (size_t)node * DD + d0);
      float hvv[4];
      #pragma unroll
      for (int r = 0; r < 4; ++r){
        const float rg = 1.f / (1.f + __expf(-(acc[0][0][ns][r] + acc[0][1][ns][r] + brz[r])));
        const float zg = 1.f / (1.f + __expf(-(acc[1][0][ns][r] + acc[1][1][ns][r] + bzz[r])));
        const float xa = (acc[2][0][ns][r] + bin[r]) + rg * (acc[2][1][ns][r] + bhn[r]);
        const float ng = 1.f - 2.f / (__expf(2.f * xa) + 1.f);   // tanh
        hvv[r] = (1.f - zg) * ng + zg * ho[r];
      }
      *(f32x4*)(h_new + (size_t)node * DD + d0) = f32x4{hvv[0], hvv[1], hvv[2], hvv[3]};
      uint32_t p0 = f2bf(hvv[0]) | (f2bf(hvv[1]) << 16);
      uint32_t p1 = f2bf(hvv[2]) | (f2bf(hvv[3]) << 16);
      *(uint2*)(hdst + (size_t)node * DD + d0) = make_uint2(p0, p1);
    }

    // --- write next tile into the other buffer; one barrier per tile ---
    if (have){
      mt[buf ^ 1][sn * 16 + scs] = mv;
      ht[buf ^ 1][sn * 16 + scs] = hv;
    }
    __syncthreads();
    buf ^= 1;
  }
}

// ---------------------------------------------------------------- launch
extern "C" void kernel_launch(void* const* d_in, const int* in_sizes, int n_in,
                              void* d_out, int out_size, void* d_ws, size_t ws_size,
                              hipStream_t stream) {
  const float* x      = (const float*)d_in[0];
  const int*   erow   = (const int*)d_in[1];
  const int*   ecol   = (const int*)d_in[2];
  const float* eval   = (const float*)d_in[3];
  const float* weight = (const float*)d_in[4];
  const float* bias_w = (const float*)d_in[5];
  const float* wih    = (const float*)d_in[6];
  const float* whh    = (const float*)d_in[7];
  const float* bih    = (const float*)d_in[8];
  const float* bhh    = (const float*)d_in[9];
  float* out = (float*)d_out;
  char* ws = (char*)d_ws;

  size_t o = 0;
  auto alloc = [&](size_t bytes)->char*{ char* p = ws + o; o += (bytes + 255) & ~(size_t)255; return p; };
  int*      counts  = (int*)     alloc((size_t)ETT * NN * 4);        // zeroed
  int*      cursor  = (int*)     alloc((size_t)ETT * NN * 4);        // zeroed
  float*    degval  = (float*)   alloc((size_t)ETT * NN * 4);        // zeroed
  int*      offsets = (int*)     alloc((size_t)ETT * (NN + 1) * 4);
  int*      bsum    = (int*)     alloc((size_t)ETT * NCH * 4);
  int*      bexc    = (int*)     alloc((size_t)ETT * NCH * 4);
  uint2*    sedge   = (uint2*)   alloc((size_t)ETT * EE * 8);
  float*    hf      = (float*)   alloc((size_t)NN * DD * 4);
  uint16_t* hbf0    = (uint16_t*)alloc((size_t)NN * DD * 2);
  uint16_t* hbf1    = (uint16_t*)alloc((size_t)NN * DD * 2);
  uint16_t* msum    = (uint16_t*)alloc((size_t)NN * DD * 2);
  uint16_t* wcatT   = (uint16_t*)alloc((size_t)TT * 128 * 512 * 2);
  uint16_t* wihb    = (uint16_t*)alloc((size_t)384 * 128 * 2);
  uint16_t* whhb    = (uint16_t*)alloc((size_t)384 * 128 * 2);
  float*    bcomb   = (float*)   alloc((size_t)256 * 4);
  (void)ws_size; (void)in_sizes; (void)n_in; (void)out_size;

  // counts/cursor/degval contiguous (each 1.6MB, 256-aligned exactly)
  hipMemsetAsync(counts, 0, (size_t)3 * ETT * NN * 4, stream);

  k_count<<<(ETT * EE + 255) / 256, 256, 0, stream>>>(erow, eval, counts, degval);
  k_blksum<<<ETT * NCH, 256, 0, stream>>>(counts, bsum);
  k_scanp<<<1, 256, 0, stream>>>(bsum, bexc, offsets);
  k_apply<<<ETT * NCH, 256, 0, stream>>>(counts, bexc, offsets);
  k_fill<<<(ETT * EE + 255) / 256, 256, 0, stream>>>(erow, ecol, eval, offsets, cursor, sedge);
  k_conv_x<<<(NN * DD / 8) / 256, 256, 0, stream>>>(x, hbf0);
  k_conv_w<<<(TT * 128 * 512 + 255) / 256, 256, 0, stream>>>(weight, wih, whh, bih, bhh,
                                                             wcatT, wihb, whhb, bcomb);

  uint16_t* hsrc = hbf0;
  uint16_t* hdst = hbf1;
  for (int t = 0; t < TT; ++t){
    k_agg_gemm<<<NN / 32, 256, 0, stream>>>(hsrc, offsets, sedge, degval,
                                            bias_w, wcatT + (size_t)t * 65536, t, msum);
    const float* hold = (t == 0) ? x : hf;
    float* hnew = (t == TT - 1) ? out : hf;
    k_gru<<<256, 512, 0, stream>>>(msum, hsrc, hdst, hold, hnew,
                                   wihb, whhb, bcomb, bih, bhh);
    uint16_t* tmp = hsrc; hsrc = hdst; hdst = tmp;
  }
}

// Round 5
// 721.412 us; speedup vs baseline: 2.0649x; 1.0724x over previous
//
#include <hip/hip_runtime.h>
#include <stdint.h>

// Problem constants (GatedGraphConv_26585847562966)
#define NN  100000   // nodes
#define DD  128      // feature dim
#define TT  3        // timesteps
#define ETT 4        // edge types
#define EE  250000   // edges per type
#define NCH 49       // scan chunks per edge type (2048 elems each)
#define GRUGRID 512  // k_gru blocks (2/CU)

typedef float  f32x4  __attribute__((ext_vector_type(4)));
typedef __bf16 bf16x8 __attribute__((ext_vector_type(8)));

__device__ __forceinline__ float bf2f(uint32_t u){ u <<= 16; return __builtin_bit_cast(float, u); }
__device__ __forceinline__ uint32_t f2bf(float f){
  uint32_t u = __builtin_bit_cast(uint32_t, f);
  return (u + 0x7FFFu + ((u >> 16) & 1u)) >> 16;   // RNE, low 16 bits valid
}
__device__ __forceinline__ f32x4 mfma16(bf16x8 a, bf16x8 b, f32x4 c){
  return __builtin_amdgcn_mfma_f32_16x16x32_bf16(a, b, c, 0, 0, 0);
}

// ---------------------------------------------------------------- CSR build
__global__ void k_count(const int* __restrict__ erow, const float* __restrict__ eval,
                        int* __restrict__ counts, float* __restrict__ degval){
  int idx = blockIdx.x * 256 + threadIdx.x;
  if (idx >= ETT * EE) return;
  int e = idx / EE;
  int row = erow[idx];
  atomicAdd(&counts[e * NN + row], 1);
  atomicAdd(&degval[e * NN + row], eval[idx]);
}

// per-chunk sums (grid = ETT*NCH blocks x 256)
__global__ void k_blksum(const int* __restrict__ counts, int* __restrict__ bsum){
  const int b = blockIdx.x, e = b / NCH, c = b % NCH;
  const int* p = counts + e * NN + c * 2048;
  int lim = NN - c * 2048; if (lim > 2048) lim = 2048;
  const int t = threadIdx.x;
  int s = 0;
  #pragma unroll
  for (int i = 0; i < 8; ++i){
    int idx = i * 256 + t;
    if (idx < lim) s += p[idx];
  }
  #pragma unroll
  for (int d = 32; d; d >>= 1) s += __shfl_down(s, d);
  __shared__ int wsum[4];
  if ((t & 63) == 0) wsum[t >> 6] = s;
  __syncthreads();
  if (t == 0) bsum[b] = wsum[0] + wsum[1] + wsum[2] + wsum[3];
}

// scan the 49 chunk-sums per edge type (1 block, wave per etype)
__global__ void k_scanp(const int* __restrict__ bsum, int* __restrict__ bexc,
                        int* __restrict__ offsets){
  const int t = threadIdx.x, wid = t >> 6, l = t & 63;
  int v = (l < NCH) ? bsum[wid * NCH + l] : 0;
  int x = v;
  #pragma unroll
  for (int d = 1; d < 64; d <<= 1){ int y = __shfl_up(x, d); if (l >= d) x += y; }
  if (l < NCH) bexc[wid * NCH + l] = x - v;
  if (l == NCH - 1) offsets[wid * (NN + 1) + NN] = x;
}

// per-chunk exclusive scan + chunk offset (grid = ETT*NCH x 256)
__global__ void k_apply(const int* __restrict__ counts, const int* __restrict__ bexc,
                        int* __restrict__ offsets){
  const int b = blockIdx.x, e = b / NCH, c = b % NCH;
  const int* p = counts + e * NN + c * 2048;
  int* off = offsets + e * (NN + 1) + c * 2048;
  int lim = NN - c * 2048; if (lim > 2048) lim = 2048;
  const int t = threadIdx.x, l = t & 63, wid = t >> 6;
  __shared__ int wt[4];
  int v[8], s = 0;
  #pragma unroll
  for (int i = 0; i < 8; ++i){
    int idx = t * 8 + i;
    v[i] = (idx < lim) ? p[idx] : 0; s += v[i];
  }
  int x = s;
  #pragma unroll
  for (int d = 1; d < 64; d <<= 1){ int y = __shfl_up(x, d); if (l >= d) x += y; }
  if (l == 63) wt[wid] = x;
  __syncthreads();
  int wexc = 0;
  #pragma unroll
  for (int k = 0; k < 4; ++k) if (k < wid) wexc += wt[k];
  int te = bexc[b] + wexc + (x - s);
  #pragma unroll
  for (int i = 0; i < 8; ++i){
    int idx = t * 8 + i;
    if (idx < lim) off[idx] = te;
    te += v[i];
  }
}

__global__ void k_fill(const int* __restrict__ erow, const int* __restrict__ ecol,
                       const float* __restrict__ eval, const int* __restrict__ offsets,
                       int* __restrict__ cursor, uint2* __restrict__ sedge){
  int idx = blockIdx.x * 256 + threadIdx.x;
  if (idx >= ETT * EE) return;
  int e = idx / EE;
  int row = erow[idx];
  int pos = atomicAdd(&cursor[e * NN + row], 1);
  int o = offsets[e * (NN + 1) + row] + pos;
  sedge[e * EE + o] = make_uint2((uint32_t)ecol[idx], __builtin_bit_cast(uint32_t, eval[idx]));
}

// ---------------------------------------------------------------- converts
__global__ void k_conv_x(const float* __restrict__ x, uint16_t* __restrict__ hbf){
  int idx = blockIdx.x * 256 + threadIdx.x;       // one uint4 (8 bf16) per thread
  const float4* xp = (const float4*)x;
  float4 a = xp[idx * 2], b = xp[idx * 2 + 1];
  uint32_t p0 = f2bf(a.x) | (f2bf(a.y) << 16);
  uint32_t p1 = f2bf(a.z) | (f2bf(a.w) << 16);
  uint32_t p2 = f2bf(b.x) | (f2bf(b.y) << 16);
  uint32_t p3 = f2bf(b.z) | (f2bf(b.w) << 16);
  ((uint4*)hbf)[idx] = make_uint4(p0, p1, p2, p3);
}

// wcatT[t][f][e*128+d] = weight[t][e][d][f]   (B^T layout: contiguous-k fragments)
__global__ void k_conv_w(const float* __restrict__ weight, const float* __restrict__ wih,
                         const float* __restrict__ whh, const float* __restrict__ bih,
                         const float* __restrict__ bhh, uint16_t* __restrict__ wcatT,
                         uint16_t* __restrict__ wihb, uint16_t* __restrict__ whhb,
                         float* __restrict__ bcomb){
  int idx = blockIdx.x * 256 + threadIdx.x;
  if (idx < TT * 128 * 512){
    int t = idx / 65536; int rem = idx - t * 65536;
    int f = rem >> 9; int u = rem & 511;
    int e = u >> 7; int d = u & 127;
    wcatT[idx] = (uint16_t)f2bf(weight[(((t * 4 + e) * 128 + d) << 7) + f]);
  }
  if (idx < 384 * 128){
    wihb[idx] = (uint16_t)f2bf(wih[idx]);
    whhb[idx] = (uint16_t)f2bf(whh[idx]);
  }
  if (idx < 256) bcomb[idx] = bih[idx] + bhh[idx];
}

// ------------------------------------------------- fused gather + GEMM1
// m_sum[n,f] = sum_{e,d} agg[e,n,d] * W[t,e,d,f] + sum_e deg[e,n]*bias_w[t,e,f]
// Gather uses 4-way edge batching: 8 independent h-row uint4 loads in flight
// per iteration (clamped indices alias an in-flight line; val=0 neutralizes).
#define ACC8(val, u, base) \
  acc[base+0] += val * bf2f(u.x & 0xffffu); acc[base+1] += val * bf2f(u.x >> 16); \
  acc[base+2] += val * bf2f(u.y & 0xffffu); acc[base+3] += val * bf2f(u.y >> 16); \
  acc[base+4] += val * bf2f(u.z & 0xffffu); acc[base+5] += val * bf2f(u.z >> 16); \
  acc[base+6] += val * bf2f(u.w & 0xffffu); acc[base+7] += val * bf2f(u.w >> 16);

__global__ __launch_bounds__(256, 4) void k_agg_gemm(
    const uint16_t* __restrict__ hbf, const int* __restrict__ offsets,
    const uint2* __restrict__ sedge, const float* __restrict__ degval,
    const float* __restrict__ bias_w, const uint16_t* __restrict__ wcatT_t,
    int tstep, uint16_t* __restrict__ m_out)
{
  __shared__ uint16_t aggT[32 * 512];             // 32 KiB, 16B-chunk XOR-swizzled
  const int tid = threadIdx.x;
  const int node0 = blockIdx.x * 32;              // 100000/32 = 3125 blocks exact

  { // gather: thread = (node nl of 32, eighth q of 16 dims)
    const int nl = tid >> 3, q = tid & 7;
    const int n = node0 + nl;
    int se[4], ne[4];
    #pragma unroll
    for (int e = 0; e < ETT; ++e){
      se[e] = offsets[e * (NN + 1) + n];
      ne[e] = offsets[e * (NN + 1) + n + 1];
    }
    #pragma unroll 1
    for (int e = 0; e < ETT; ++e){
      float acc[16];
      #pragma unroll
      for (int i = 0; i < 16; ++i) acc[i] = 0.f;
      const int s = se[e], en = ne[e];
      const uint2* ep = sedge + (size_t)e * EE;
      #pragma unroll 1
      for (int i = s; i < en; i += 4){
        const int last = en - 1;
        const int i1 = (i + 1 < last) ? i + 1 : last;
        const int i2 = (i + 2 < last) ? i + 2 : last;
        const int i3 = (i + 3 < last) ? i + 3 : last;
        const uint2 cv0 = ep[i], cv1 = ep[i1], cv2 = ep[i2], cv3 = ep[i3];
        const float v0 = __builtin_bit_cast(float, cv0.y);
        const float v1 = (i + 1 <= last) ? __builtin_bit_cast(float, cv1.y) : 0.f;
        const float v2 = (i + 2 <= last) ? __builtin_bit_cast(float, cv2.y) : 0.f;
        const float v3 = (i + 3 <= last) ? __builtin_bit_cast(float, cv3.y) : 0.f;
        const uint4* p0 = (const uint4*)(hbf + (size_t)cv0.x * DD + q * 16);
        const uint4* p1 = (const uint4*)(hbf + (size_t)cv1.x * DD + q * 16);
        const uint4* p2 = (const uint4*)(hbf + (size_t)cv2.x * DD + q * 16);
        const uint4* p3 = (const uint4*)(hbf + (size_t)cv3.x * DD + q * 16);
        const uint4 a0 = p0[0], b0 = p0[1];
        const uint4 a1 = p1[0], b1 = p1[1];
        const uint4 a2 = p2[0], b2 = p2[1];
        const uint4 a3 = p3[0], b3 = p3[1];
        ACC8(v0, a0, 0); ACC8(v0, b0, 8);
        ACC8(v1, a1, 0); ACC8(v1, b1, 8);
        ACC8(v2, a2, 0); ACC8(v2, b2, 8);
        ACC8(v3, a3, 0); ACC8(v3, b3, 8);
      }
      #pragma unroll
      for (int c2 = 0; c2 < 2; ++c2){
        const int c  = e * 16 + q * 2 + c2;       // logical 16B chunk (0..63)
        const int cs = c ^ (nl & 7);
        uint32_t p0 = f2bf(acc[c2*8+0]) | (f2bf(acc[c2*8+1]) << 16);
        uint32_t p1 = f2bf(acc[c2*8+2]) | (f2bf(acc[c2*8+3]) << 16);
        uint32_t p2 = f2bf(acc[c2*8+4]) | (f2bf(acc[c2*8+5]) << 16);
        uint32_t p3 = f2bf(acc[c2*8+6]) | (f2bf(acc[c2*8+7]) << 16);
        *(uint4*)&aggT[nl * 512 + cs * 8] = make_uint4(p0, p1, p2, p3);
      }
    }
  }
  __syncthreads();

  // GEMM: C[32x128] = aggT[32x512] * Wcat[512x128]
  // wave w: row-tile rt = w&1 (16 rows), f-half fh = w>>1 (64 cols = 4 f-tiles)
  const int lane = tid & 63, w = tid >> 6;
  const int rlo = lane & 15, kg = lane >> 4;
  const int rt = w & 1, fh = w >> 1;
  const int rowA = rt * 16 + rlo;
  f32x4 C[4];
  #pragma unroll
  for (int i = 0; i < 4; ++i) C[i] = f32x4{0.f, 0.f, 0.f, 0.f};

  #pragma unroll
  for (int ks = 0; ks < 16; ++ks){
    const int cs = (ks * 4 + kg) ^ (rowA & 7);
    bf16x8 a = __builtin_bit_cast(bf16x8, *(const uint4*)&aggT[rowA * 512 + cs * 8]);
    #pragma unroll
    for (int ft = 0; ft < 4; ++ft){
      const int f = fh * 64 + ft * 16 + rlo;
      bf16x8 b = __builtin_bit_cast(bf16x8, *(const uint4*)(wcatT_t + (size_t)f * 512 + ks * 32 + kg * 8));
      C[ft] = mfma16(a, b, C[ft]);
    }
  }

  const float* bwt = bias_w + tstep * (ETT * DD);
  float dv[4][4];
  #pragma unroll
  for (int r = 0; r < 4; ++r){
    const int n2 = node0 + rt * 16 + kg * 4 + r;
    #pragma unroll
    for (int e = 0; e < 4; ++e) dv[e][r] = degval[e * NN + n2];
  }
  #pragma unroll
  for (int ft = 0; ft < 4; ++ft){
    const int f = fh * 64 + ft * 16 + rlo;
    const float b0 = bwt[f], b1 = bwt[128 + f], b2 = bwt[256 + f], b3 = bwt[384 + f];
    #pragma unroll
    for (int r = 0; r < 4; ++r){
      const int n2 = node0 + rt * 16 + kg * 4 + r;
      const float bias = dv[0][r]*b0 + dv[1][r]*b1 + dv[2][r]*b2 + dv[3][r]*b3;
      m_out[(size_t)n2 * DD + f] = (uint16_t)f2bf(C[ft][r] + bias);
    }
  }
}

// ------------------------------------------------- GRU: weights in VGPRs
// Block = 512 thr (8 waves). Wave w owns dims [w*16, w*16+16) for all 3 gates,
// BOTH matrices: 24 bf16x8 A-fragments = 96 VGPRs, loaded ONCE from global.
// Block grid-strides over 32-node tiles; per tile, m_sum/h rows are staged into
// a double-buffered 2x(8KB+8KB) XOR-swizzled LDS tile (each row read once
// device-wide -> no cross-XCD refetch). Lane (rlo,kg) ends up with all six
// gate pre-activations for node (tile*32+ns*16+rlo), d = w*16+kg*4+r -> full
// GRU epilogue in-lane. hbf ping-pongs across dispatches.
__global__ __launch_bounds__(512, 2) void k_gru(
    const uint16_t* __restrict__ m_sum, const uint16_t* __restrict__ hsrc,
    uint16_t* __restrict__ hdst, const float* __restrict__ h_old,
    float* __restrict__ h_new, const uint16_t* __restrict__ wihb,
    const uint16_t* __restrict__ whhb, const float* __restrict__ bcomb,
    const float* __restrict__ b_ih, const float* __restrict__ b_hh)
{
  __shared__ uint4 mt[2][512];                    // [buf][node*16 + chunk] 8KB each
  __shared__ uint4 ht[2][512];
  const int tid = threadIdx.x;
  const int lane = tid & 63, w = tid >> 6;
  const int rlo = lane & 15, kg = lane >> 4;

  // --- preload weight fragments (persistent in VGPRs) ---
  bf16x8 wa[3][4], wb[3][4];                      // [gate][ks]
  #pragma unroll
  for (int g = 0; g < 3; ++g){
    const int j = g * 128 + w * 16 + rlo;
    #pragma unroll
    for (int ks = 0; ks < 4; ++ks){
      wa[g][ks] = __builtin_bit_cast(bf16x8, *(const uint4*)(wihb + j * 128 + ks * 32 + kg * 8));
      wb[g][ks] = __builtin_bit_cast(bf16x8, *(const uint4*)(whhb + j * 128 + ks * 32 + kg * 8));
    }
  }
  // --- per-lane output dims + biases (constant over tiles) ---
  const int d0 = w * 16 + kg * 4;
  const f32x4 brz = *(const f32x4*)(bcomb + d0);
  const f32x4 bzz = *(const f32x4*)(bcomb + 128 + d0);
  const f32x4 bin = *(const f32x4*)(b_ih + 256 + d0);
  const f32x4 bhn = *(const f32x4*)(b_hh + 256 + d0);

  // --- staging map: thread -> (node sn, LDS slot scs), source chunk sc ---
  const int sn  = tid >> 4;                       // 0..31
  const int scs = tid & 15;                       // swizzled slot
  const int sc  = scs ^ (sn & 7);                 // logical chunk (involution)

  const int NT = NN / 32;                         // 3125
  int tile = blockIdx.x;
  { // prologue: stage tile 0 into buf 0
    const size_t base = ((size_t)(tile * 32 + sn)) * DD + sc * 8;
    mt[0][sn * 16 + scs] = *(const uint4*)(m_sum + base);
    ht[0][sn * 16 + scs] = *(const uint4*)(hsrc + base);
  }
  __syncthreads();

  int buf = 0;
  #pragma unroll 1
  for (; tile < NT; tile += GRUGRID){
    // issue next tile's stage loads (consumed after the barrier below)
    const int ntile = tile + GRUGRID;
    const bool have = ntile < NT;                 // block-uniform
    uint4 mv, hv;
    if (have){
      const size_t nbase = ((size_t)(ntile * 32 + sn)) * DD + sc * 8;
      mv = *(const uint4*)(m_sum + nbase);
      hv = *(const uint4*)(hsrc + nbase);
    }

    // --- MFMA phase: 48 MFMAs per wave from LDS B-fragments ---
    f32x4 acc[3][2][2];                           // [gate][mat][nsub]
    #pragma unroll
    for (int g = 0; g < 3; ++g)
      #pragma unroll
      for (int m = 0; m < 2; ++m)
        #pragma unroll
        for (int ns = 0; ns < 2; ++ns) acc[g][m][ns] = f32x4{0.f,0.f,0.f,0.f};

    #pragma unroll
    for (int ks = 0; ks < 4; ++ks){
      #pragma unroll
      for (int ns = 0; ns < 2; ++ns){
        const int node = ns * 16 + rlo;
        const int cs = (ks * 4 + kg) ^ (node & 7);
        const bf16x8 bm = __builtin_bit_cast(bf16x8, mt[buf][node * 16 + cs]);
        const bf16x8 bh = __builtin_bit_cast(bf16x8, ht[buf][node * 16 + cs]);
        #pragma unroll
        for (int g = 0; g < 3; ++g){
          acc[g][0][ns] = mfma16(wa[g][ks], bm, acc[g][0][ns]);
          acc[g][1][ns] = mfma16(wb[g][ks], bh, acc[g][1][ns]);
        }
      }
    }

    // --- GRU epilogue, fully in-lane ---
    #pragma unroll
    for (int ns = 0; ns < 2; ++ns){
      const int node = tile * 32 + ns * 16 + rlo;
      const f32x4 ho = *(const f32x4*)(h_old + (size_t)node * DD + d0);
      float hvv[4];
      #pragma unroll
      for (int r = 0; r < 4; ++r){
        const float rg = 1.f / (1.f + __expf(-(acc[0][0][ns][r] + acc[0][1][ns][r] + brz[r])));
        const float zg = 1.f / (1.f + __expf(-(acc[1][0][ns][r] + acc[1][1][ns][r] + bzz[r])));
        const float xa = (acc[2][0][ns][r] + bin[r]) + rg * (acc[2][1][ns][r] + bhn[r]);
        const float ng = 1.f - 2.f / (__expf(2.f * xa) + 1.f);   // tanh
        hvv[r] = (1.f - zg) * ng + zg * ho[r];
      }
      *(f32x4*)(h_new + (size_t)node * DD + d0) = f32x4{hvv[0], hvv[1], hvv[2], hvv[3]};
      uint32_t p0 = f2bf(hvv[0]) | (f2bf(hvv[1]) << 16);
      uint32_t p1 = f2bf(hvv[2]) | (f2bf(hvv[3]) << 16);
      *(uint2*)(hdst + (size_t)node * DD + d0) = make_uint2(p0, p1);
    }

    // --- write next tile into the other buffer; one barrier per tile ---
    if (have){
      mt[buf ^ 1][sn * 16 + scs] = mv;
      ht[buf ^ 1][sn * 16 + scs] = hv;
    }
    __syncthreads();
    buf ^= 1;
  }
}

// ---------------------------------------------------------------- launch
extern "C" void kernel_launch(void* const* d_in, const int* in_sizes, int n_in,
                              void* d_out, int out_size, void* d_ws, size_t ws_size,
                              hipStream_t stream) {
  const float* x      = (const float*)d_in[0];
  const int*   erow   = (const int*)d_in[1];
  const int*   ecol   = (const int*)d_in[2];
  const float* eval   = (const float*)d_in[3];
  const float* weight = (const float*)d_in[4];
  const float* bias_w = (const float*)d_in[5];
  const float* wih    = (const float*)d_in[6];
  const float* whh    = (const float*)d_in[7];
  const float* bih    = (const float*)d_in[8];
  const float* bhh    = (const float*)d_in[9];
  float* out = (float*)d_out;
  char* ws = (char*)d_ws;

  size_t o = 0;
  auto alloc = [&](size_t bytes)->char*{ char* p = ws + o; o += (bytes + 255) & ~(size_t)255; return p; };
  int*      counts  = (int*)     alloc((size_t)ETT * NN * 4);        // zeroed
  int*      cursor  = (int*)     alloc((size_t)ETT * NN * 4);        // zeroed
  float*    degval  = (float*)   alloc((size_t)ETT * NN * 4);        // zeroed
  int*      offsets = (int*)     alloc((size_t)ETT * (NN + 1) * 4);
  int*      bsum    = (int*)     alloc((size_t)ETT * NCH * 4);
  int*      bexc    = (int*)     alloc((size_t)ETT * NCH * 4);
  uint2*    sedge   = (uint2*)   alloc((size_t)ETT * EE * 8);
  float*    hf      = (float*)   alloc((size_t)NN * DD * 4);
  uint16_t* hbf0    = (uint16_t*)alloc((size_t)NN * DD * 2);
  uint16_t* hbf1    = (uint16_t*)alloc((size_t)NN * DD * 2);
  uint16_t* msum    = (uint16_t*)alloc((size_t)NN * DD * 2);
  uint16_t* wcatT   = (uint16_t*)alloc((size_t)TT * 128 * 512 * 2);
  uint16_t* wihb    = (uint16_t*)alloc((size_t)384 * 128 * 2);
  uint16_t* whhb    = (uint16_t*)alloc((size_t)384 * 128 * 2);
  float*    bcomb   = (float*)   alloc((size_t)256 * 4);
  (void)ws_size; (void)in_sizes; (void)n_in; (void)out_size;

  // counts/cursor/degval contiguous (each 1.6MB, 256-aligned exactly)
  hipMemsetAsync(counts, 0, (size_t)3 * ETT * NN * 4, stream);

  k_count<<<(ETT * EE + 255) / 256, 256, 0, stream>>>(erow, eval, counts, degval);
  k_blksum<<<ETT * NCH, 256, 0, stream>>>(counts, bsum);
  k_scanp<<<1, 256, 0, stream>>>(bsum, bexc, offsets);
  k_apply<<<ETT * NCH, 256, 0, stream>>>(counts, bexc, offsets);
  k_fill<<<(ETT * EE + 255) / 256, 256, 0, stream>>>(erow, ecol, eval, offsets, cursor, sedge);
  k_conv_x<<<(NN * DD / 8) / 256, 256, 0, stream>>>(x, hbf0);
  k_conv_w<<<(TT * 128 * 512 + 255) / 256, 256, 0, stream>>>(weight, wih, whh, bih, bhh,
                                                             wcatT, wihb, whhb, bcomb);

  uint16_t* hsrc = hbf0;
  uint16_t* hdst = hbf1;
  for (int t = 0; t < TT; ++t){
    k_agg_gemm<<<NN / 32, 256, 0, stream>>>(hsrc, offsets, sedge, degval,
                                            bias_w, wcatT + (size_t)t * 65536, t, msum);
    const float* hold = (t == 0) ? x : hf;
    float* hnew = (t == TT - 1) ? out : hf;
    k_gru<<<GRUGRID, 512, 0, stream>>>(msum, hsrc, hdst, hold, hnew,
                                       wihb, whhb, bcomb, bih, bhh);
    uint16_t* tmp = hsrc; hsrc = hdst; hdst = tmp;
  }
}